// Round 2
// baseline (277.924 us; speedup 1.0000x reference)
//
#include <hip/hip_runtime.h>

#define N_EDGES 800000
#define N_NODES 50000
#define D 64                 // D_FEAT == EDGE_DIM == 64

typedef __attribute__((ext_vector_type(8))) short bf16x8;  // 8 bf16 = 16 B
typedef __attribute__((ext_vector_type(4))) float f32x4;

#if __has_builtin(__builtin_amdgcn_exp2f)
#define EXP2F(x) __builtin_amdgcn_exp2f(x)
#else
#define EXP2F(x) __expf(0.69314718055994531f * (x))
#endif

// f32 -> bf16 round-to-nearest-even (finite inputs)
__device__ __forceinline__ unsigned short f2bf(float f) {
    unsigned int u = __float_as_uint(f);
    u += 0x7fffu + ((u >> 16) & 1u);
    return (unsigned short)(u >> 16);
}
__device__ __forceinline__ unsigned int pack2(float a, float b) {
    return (unsigned int)f2bf(a) | ((unsigned int)f2bf(b) << 16);
}

// W (128x64 f32) -> per-lane MFMA fragment order: 1024 x 16B entries.
// entry idx = (ki*4+nt)*64 + l, l = q*16+m:
//   frag[j] = bf16(W[ki*32+q*8+j][nt*16+m]), j=0..7
// ki in {0,1} covers W rows 0..63 (recv half), {2,3} rows 64..127 (send half).
__global__ __launch_bounds__(256) void prep_w(
    const float* __restrict__ W, unsigned short* __restrict__ wfrag)
{
#pragma unroll
    for (int i = 0; i < 4; ++i) {
        const int idx = i * 256 + threadIdx.x;     // 0..1023
        const int ki = idx >> 8;
        const int nt = (idx >> 6) & 3;
        const int l  = idx & 63;
        const int m  = l & 15, q = l >> 4;
        const int kbase = ki * 32 + q * 8;
        const int n = nt * 16 + m;
        unsigned short* dst = wfrag + idx * 8;
#pragma unroll
        for (int j = 0; j < 8; ++j)
            dst[j] = f2bf(W[(kbase + j) * D + n]);
    }
}

// Per-node projection: Pr = nf @ W[0:64], Ps = nf @ W[64:128]  (both [N][64] f32).
// Wave = 64 nodes; operand-swapped MFMA (verified layout from the edge kernel):
//   acc[mt][nt][r] = P[node = n0+mt*16+m][feat = nt*16+q*4+r]
// Stores are CACHED (not NT): Pr/Ps are re-read by edge_act.
__global__ __launch_bounds__(256) void node_proj(
    const float* __restrict__ nf, const bf16x8* __restrict__ wfrag,
    float* __restrict__ Pr, float* __restrict__ Ps)
{
    __shared__ bf16x8 lds_b[1024];                // 16 KB, fragment order
#pragma unroll
    for (int i = 0; i < 4; ++i) {
        const int idx = i * 256 + threadIdx.x;
        lds_b[idx] = wfrag[idx];
    }
    __syncthreads();

    const int lane = threadIdx.x & 63;
    const int m    = lane & 15;
    const int q    = lane >> 4;
    const int wid  = blockIdx.x * 4 + (threadIdx.x >> 6);
    const int n0   = wid * 64;

    // A fragments: contiguous f32 node rows -> bf16. a[kk][mt]: k = kk*32+q*8+j.
    bf16x8 a[2][4];
#pragma unroll
    for (int mt = 0; mt < 4; ++mt) {
        const int row = n0 + mt * 16 + m;
        const int rl  = row < N_NODES ? row : N_NODES - 1;   // clamp tail loads
        const float* rp = nf + (long)rl * D;
#pragma unroll
        for (int kk = 0; kk < 2; ++kk) {
            const float4 lo = *(const float4*)(rp + kk * 32 + q * 8);
            const float4 hi = *(const float4*)(rp + kk * 32 + q * 8 + 4);
            union { bf16x8 v; unsigned int u[4]; } cv;
            cv.u[0] = pack2(lo.x, lo.y);
            cv.u[1] = pack2(lo.z, lo.w);
            cv.u[2] = pack2(hi.x, hi.y);
            cv.u[3] = pack2(hi.z, hi.w);
            a[kk][mt] = cv.v;
        }
    }

#pragma unroll
    for (int tab = 0; tab < 2; ++tab) {            // 0: recv half -> Pr, 1: send -> Ps
        f32x4 acc[4][4];
#pragma unroll
        for (int mt = 0; mt < 4; ++mt)
#pragma unroll
            for (int nt = 0; nt < 4; ++nt)
                acc[mt][nt] = (f32x4)0.0f;

#pragma unroll
        for (int ki2 = 0; ki2 < 2; ++ki2) {
#pragma unroll
            for (int nt = 0; nt < 4; ++nt) {
                const bf16x8 bf = lds_b[((tab * 2 + ki2) * 4 + nt) * 64 + lane];
#pragma unroll
                for (int mt = 0; mt < 4; ++mt)
                    acc[mt][nt] = __builtin_amdgcn_mfma_f32_16x16x32_bf16(
                        bf, a[ki2][mt], acc[mt][nt], 0, 0, 0);
            }
        }

        float* __restrict__ P = tab ? Ps : Pr;
#pragma unroll
        for (int mt = 0; mt < 4; ++mt) {
            const int row = n0 + mt * 16 + m;
            if (row < N_NODES) {
                float* op = P + (long)row * D + q * 4;
#pragma unroll
                for (int nt = 0; nt < 4; ++nt)
                    *(f32x4*)(op + nt * 16) = acc[mt][nt];
            }
        }
    }
}

// Streaming edge kernel: out[e] = tanh(Pr[recv[e]] + Ps[send[e]] + b).
// 4 lanes per edge; lane c owns features {s4*16 + c*4 .. +3}, s4=0..3, so every
// load/store instruction is 16 contiguous 64B segments (fully coalesced).
// ~45 VGPR, no LDS -> 8 waves/SIMD to hide the random-row gather latency.
__global__ __launch_bounds__(256) void edge_act(
    const float* __restrict__ Pr, const float* __restrict__ Ps,
    const int*   __restrict__ senders, const int* __restrict__ receivers,
    const float* __restrict__ bias, float* __restrict__ out)
{
    const int t = blockIdx.x * 256 + threadIdx.x;  // 3.2M threads exact
    const int e = t >> 2;
    const int c = t & 3;

    const int r = receivers[e];
    const int s = senders[e];
    const float* pr = Pr + (long)r * D + c * 4;
    const float* ps = Ps + (long)s * D + c * 4;
    float*       op = out + (long)e * D + c * 4;

    // Issue all 8 gathers (+bias) before computing: independent -> one wait.
    f32x4 pa[4], pb[4], bb[4];
#pragma unroll
    for (int s4 = 0; s4 < 4; ++s4) {
        pa[s4] = *(const f32x4*)(pr + s4 * 16);
        pb[s4] = *(const f32x4*)(ps + s4 * 16);
        bb[s4] = *(const f32x4*)(bias + s4 * 16 + c * 4);
    }

    const float C2L = 2.8853900817779268f;         // 2*log2(e)
#pragma unroll
    for (int s4 = 0; s4 < 4; ++s4) {
        const f32x4 x = pa[s4] + pb[s4];
        f32x4 y;
#pragma unroll
        for (int k = 0; k < 4; ++k) {
            const float tt = EXP2F(__builtin_fmaf(x[k], C2L, bb[s4][k] * C2L));
            const float rc = __builtin_amdgcn_rcpf(tt + 1.0f);
            y[k] = __builtin_fmaf(-2.0f, rc, 1.0f);     // tanh, saturates to +/-1
        }
        __builtin_nontemporal_store(y, (f32x4*)(op + s4 * 16));  // out never re-read
    }
}

extern "C" void kernel_launch(void* const* d_in, const int* in_sizes, int n_in,
                              void* d_out, int out_size, void* d_ws, size_t ws_size,
                              hipStream_t stream) {
    const float* node_feats = (const float*)d_in[0];
    const int*   senders    = (const int*)d_in[1];
    const int*   receivers  = (const int*)d_in[2];
    const float* W          = (const float*)d_in[3];
    const float* bias       = (const float*)d_in[4];
    float*       out        = (float*)d_out;

    // ws layout: Pr [50000][64] f32 (12.8 MB) | Ps same | wfrag 16 KB
    float* Pr = (float*)d_ws;
    float* Ps = Pr + (size_t)N_NODES * D;
    unsigned short* wfrag = (unsigned short*)(Ps + (size_t)N_NODES * D);

    prep_w<<<1, 256, 0, stream>>>(W, wfrag);

    const int np_blocks = (N_NODES + 255) / 256;   // 196: 4 waves/block, 64 nodes/wave
    node_proj<<<np_blocks, 256, 0, stream>>>(node_feats, (const bf16x8*)wfrag, Pr, Ps);

    const int ea_blocks = (N_EDGES * 4) / 256;     // 12500 exact
    edge_act<<<ea_blocks, 256, 0, stream>>>(Pr, Ps, senders, receivers, bias, out);
}

// Round 3
// 276.142 us; speedup vs baseline: 1.0065x; 1.0065x over previous
//
#include <hip/hip_runtime.h>

#define N_EDGES 800000
#define N_NODES 50000
#define D 64                 // D_FEAT == EDGE_DIM == 64

typedef __attribute__((ext_vector_type(8))) short bf16x8;  // 8 bf16 = 16 B
typedef __attribute__((ext_vector_type(4))) float f32x4;

#if __has_builtin(__builtin_amdgcn_exp2f)
#define EXP2F(x) __builtin_amdgcn_exp2f(x)
#else
#define EXP2F(x) __expf(0.69314718055994531f * (x))
#endif

// f32 -> bf16 round-to-nearest-even (finite inputs)
__device__ __forceinline__ unsigned short f2bf(float f) {
    unsigned int u = __float_as_uint(f);
    u += 0x7fffu + ((u >> 16) & 1u);
    return (unsigned short)(u >> 16);
}
__device__ __forceinline__ unsigned int pack2(float a, float b) {
    return (unsigned int)f2bf(a) | ((unsigned int)f2bf(b) << 16);
}

// Per-node projection: Pr = nf @ W[0:64], Ps = nf @ W[64:128]  (both [N][64] f32).
// Each block builds the W MFMA-fragment table (16 KB) in its own LDS directly
// from W (32 KB f32, L2-hot after block 0) — no separate prep kernel, no
// single-block serial dispatch (round-2 lesson).
// Fragment order: idx = (ki*4+nt)*64 + l, l = q*16+m:
//   frag[j] = bf16(W[ki*32+q*8+j][nt*16+m]), j=0..7
// Operand-swapped MFMA (layout verified in rounds 0-2):
//   acc[mt][nt][r] = P[node = n0+mt*16+m][feat = nt*16+q*4+r]
// Stores are CACHED (not NT): Pr/Ps are re-read by edge_act.
__global__ __launch_bounds__(256) void node_proj(
    const float* __restrict__ nf, const float* __restrict__ W,
    float* __restrict__ Pr, float* __restrict__ Ps)
{
    __shared__ bf16x8 lds_b[1024];                // 16 KB, fragment order

#pragma unroll
    for (int i = 0; i < 4; ++i) {
        const int idx = i * 256 + threadIdx.x;     // 0..1023
        const int ki = idx >> 8;
        const int nt = (idx >> 6) & 3;
        const int l  = idx & 63;
        const int mm = l & 15, qq = l >> 4;
        const int kbase = ki * 32 + qq * 8;
        const int n = nt * 16 + mm;
        union { bf16x8 v; unsigned short h[8]; } cv;
#pragma unroll
        for (int j = 0; j < 8; ++j)
            cv.h[j] = f2bf(W[(kbase + j) * D + n]);
        lds_b[idx] = cv.v;
    }
    __syncthreads();

    const int lane = threadIdx.x & 63;
    const int m    = lane & 15;
    const int q    = lane >> 4;
    const int wid  = blockIdx.x * 4 + (threadIdx.x >> 6);
    const int n0   = wid * 64;

    // A fragments: contiguous f32 node rows -> bf16. a[kk][mt]: k = kk*32+q*8+j.
    bf16x8 a[2][4];
#pragma unroll
    for (int mt = 0; mt < 4; ++mt) {
        const int row = n0 + mt * 16 + m;
        const int rl  = row < N_NODES ? row : N_NODES - 1;   // clamp tail loads
        const float* rp = nf + (long)rl * D;
#pragma unroll
        for (int kk = 0; kk < 2; ++kk) {
            const float4 lo = *(const float4*)(rp + kk * 32 + q * 8);
            const float4 hi = *(const float4*)(rp + kk * 32 + q * 8 + 4);
            union { bf16x8 v; unsigned int u[4]; } cv;
            cv.u[0] = pack2(lo.x, lo.y);
            cv.u[1] = pack2(lo.z, lo.w);
            cv.u[2] = pack2(hi.x, hi.y);
            cv.u[3] = pack2(hi.z, hi.w);
            a[kk][mt] = cv.v;
        }
    }

#pragma unroll
    for (int tab = 0; tab < 2; ++tab) {            // 0: recv half -> Pr, 1: send -> Ps
        f32x4 acc[4][4];
#pragma unroll
        for (int mt = 0; mt < 4; ++mt)
#pragma unroll
            for (int nt = 0; nt < 4; ++nt)
                acc[mt][nt] = (f32x4)0.0f;

#pragma unroll
        for (int ki2 = 0; ki2 < 2; ++ki2) {
#pragma unroll
            for (int nt = 0; nt < 4; ++nt) {
                const bf16x8 bf = lds_b[((tab * 2 + ki2) * 4 + nt) * 64 + lane];
#pragma unroll
                for (int mt = 0; mt < 4; ++mt)
                    acc[mt][nt] = __builtin_amdgcn_mfma_f32_16x16x32_bf16(
                        bf, a[ki2][mt], acc[mt][nt], 0, 0, 0);
            }
        }

        float* __restrict__ P = tab ? Ps : Pr;
#pragma unroll
        for (int mt = 0; mt < 4; ++mt) {
            const int row = n0 + mt * 16 + m;
            if (row < N_NODES) {
                float* op = P + (long)row * D + q * 4;
#pragma unroll
                for (int nt = 0; nt < 4; ++nt)
                    *(f32x4*)(op + nt * 16) = acc[mt][nt];
            }
        }
    }
}

// Streaming edge kernel: out[e] = tanh(Pr[recv[e]] + Ps[send[e]] + b).
// 4 lanes per edge; lane c owns features {s4*16 + c*4 .. +3}, s4=0..3, so every
// load/store instruction is 16 contiguous 64B segments (fully coalesced).
// ~45 VGPR, no LDS -> 8 waves/SIMD to hide the random-row gather latency.
__global__ __launch_bounds__(256) void edge_act(
    const float* __restrict__ Pr, const float* __restrict__ Ps,
    const int*   __restrict__ senders, const int* __restrict__ receivers,
    const float* __restrict__ bias, float* __restrict__ out)
{
    const int t = blockIdx.x * 256 + threadIdx.x;  // 3.2M threads exact
    const int e = t >> 2;
    const int c = t & 3;

    const int r = receivers[e];
    const int s = senders[e];
    const float* pr = Pr + (long)r * D + c * 4;
    const float* ps = Ps + (long)s * D + c * 4;
    float*       op = out + (long)e * D + c * 4;

    // Issue all 8 gathers (+bias) before computing: independent -> one wait.
    f32x4 pa[4], pb[4], bb[4];
#pragma unroll
    for (int s4 = 0; s4 < 4; ++s4) {
        pa[s4] = *(const f32x4*)(pr + s4 * 16);
        pb[s4] = *(const f32x4*)(ps + s4 * 16);
        bb[s4] = *(const f32x4*)(bias + s4 * 16 + c * 4);
    }

    const float C2L = 2.8853900817779268f;         // 2*log2(e)
#pragma unroll
    for (int s4 = 0; s4 < 4; ++s4) {
        const f32x4 x = pa[s4] + pb[s4];
        f32x4 y;
#pragma unroll
        for (int k = 0; k < 4; ++k) {
            const float tt = EXP2F(__builtin_fmaf(x[k], C2L, bb[s4][k] * C2L));
            const float rc = __builtin_amdgcn_rcpf(tt + 1.0f);
            y[k] = __builtin_fmaf(-2.0f, rc, 1.0f);     // tanh, saturates to +/-1
        }
        __builtin_nontemporal_store(y, (f32x4*)(op + s4 * 16));  // out never re-read
    }
}

extern "C" void kernel_launch(void* const* d_in, const int* in_sizes, int n_in,
                              void* d_out, int out_size, void* d_ws, size_t ws_size,
                              hipStream_t stream) {
    const float* node_feats = (const float*)d_in[0];
    const int*   senders    = (const int*)d_in[1];
    const int*   receivers  = (const int*)d_in[2];
    const float* W          = (const float*)d_in[3];
    const float* bias       = (const float*)d_in[4];
    float*       out        = (float*)d_out;

    // ws layout: Pr [50000][64] f32 (12.8 MB) | Ps same
    float* Pr = (float*)d_ws;
    float* Ps = Pr + (size_t)N_NODES * D;

    const int np_blocks = (N_NODES + 255) / 256;   // 196: 4 waves/block, 64 nodes/wave
    node_proj<<<np_blocks, 256, 0, stream>>>(node_feats, W, Pr, Ps);

    const int ea_blocks = (N_EDGES * 4) / 256;     // 12500 exact
    edge_act<<<ea_blocks, 256, 0, stream>>>(Pr, Ps, senders, receivers, bias, out);
}